// Round 4
// baseline (4368.946 us; speedup 1.0000x reference)
//
#include <hip/hip_runtime.h>
#include <stdint.h>

typedef unsigned int u32;

#define Bn 4
#define Cc 512
#define Hh 96
#define Ww 96
#define HWc (Hh*Ww)   // 9216
#define AH 11
#define Rr 512

// one block per ROI; thread t owns channel t (512 threads)
__global__ __launch_bounds__(512, 1)
void roi_align_max_kernel(const float* __restrict__ feat,
                          const float* __restrict__ rois,
                          float* __restrict__ out)
{
  __shared__ int   s_roff[AH][6];
  __shared__ float s_rw  [AH][6];
  __shared__ int   s_coff[AH][6];
  __shared__ float s_cw  [AH][6];
  __shared__ int   s_b;
  __shared__ __align__(16) float s_out[Cc*25];   // 51200 B staged output

  const int t = threadIdx.x;
  const int r = blockIdx.x;

  // zero-init weight tables (unwritten tail entries must be 0)
  if (t < AH*6){
    ((float*)s_rw)[t] = 0.0f;  ((int*)s_roff)[t] = 0;
    ((float*)s_cw)[t] = 0.0f;  ((int*)s_coff)[t] = 0;
  }
  if (t == 0){
    int b = (int)rois[r*5+0];
    s_b = min(max(b, 0), Bn-1);     // defensive: never OOB
  }
  __syncthreads();

  // ---- geometry: threads 0..10 -> rows (ph), threads 64..74 -> cols (pw) ----
  if (t < AH || (t >= 64 && t < 64+AH)){
    const bool isrow = (t < AH);
    const int  p = isrow ? t : t-64;
    const float* rp = rois + r*5;
    const float c1 = rp[isrow?2:1], c2 = rp[isrow?4:3];
    // replicate np float32 ops exactly (no fp contraction at validity boundaries)
    float lo  = __fmul_rn(c1, 0.125f);
    float hi  = __fmul_rn(c2, 0.125f);
    float ext = fmaxf(__fsub_rn(hi,lo), 0.0f);
    float bin = __fdiv_rn(ext, 10.0f);
    float ctr = __fadd_rn(lo, __fmul_rn((float)p, bin));
    float strd = fmaxf(1.0f, rintf(__fdiv_rn(bin, 3.0f)));   // half-even == jnp.round
    bool ok = (ctr >= 0.0f) && (ctr < 96.0f);
    int rws[6]; float wts[6]; int nv=0;
    #pragma unroll
    for (int s=0;s<3;++s){
      float cc = __fadd_rn(ctr, __fmul_rn((float)(s-1), strd));
      bool v = (cc >= 0.0f) && (cc < 96.0f);
      float fl = fminf(fmaxf(floorf(cc),0.0f),94.0f);
      float fr = __fsub_rn(cc, fl);
      int ri = (int)fl;
      rws[2*s]=ri; rws[2*s+1]=ri+1;
      wts[2*s]  = v ? __fsub_rn(1.0f,fr) : 0.0f;
      wts[2*s+1]= v ? fr : 0.0f;
      nv += v?1:0;
    }
    float sc = ok ? (1.0f/(float)nv) : 0.0f;   // folds center_ok + 1/cnt (separable)
    // merge duplicate rows (stride==1 overlap) + drop zero weights
    int cr[6]; float cw[6]; int n=0;
    for (int k=0;k<6;++k){
      float wk=wts[k]; if (wk==0.0f) continue;
      if (n>0 && cr[n-1]==rws[k]) cw[n-1]+=wk;
      else { cr[n]=rws[k]; cw[n]=wk; ++n; }
    }
    const int mul = isrow ? Ww : 1;
    for (int k=0;k<n;++k){
      int off = cr[k]*mul;
      float wv = cw[k]*sc;
      if (isrow){ s_roff[p][k]=off; s_rw[p][k]=wv; }
      else      { s_coff[p][k]=off; s_cw[p][k]=wv; }
    }
  }
  __syncthreads();

  // ---- per-channel gather + fused 3x3/s2 maxpool (all in registers) ----
  const float* f0 = feat + ((size_t)s_b*Cc + t)*HWc;
  float awin[5];
  for (int ph=0; ph<AH; ++ph){
    float binrow[AH];
    #pragma unroll
    for (int pw=0; pw<AH; ++pw){
      float acc = 0.0f;
      #pragma unroll
      for (int ai=0; ai<6; ++ai){
        float ra = s_rw[ph][ai];
        if (ra == 0.0f) continue;          // block-uniform skip
        int ro = s_roff[ph][ai];
        #pragma unroll
        for (int bi=0; bi<6; ++bi){
          float cb = s_cw[pw][bi];
          if (cb == 0.0f) continue;
          acc = fmaf(ra*cb, f0[ro + s_coff[pw][bi]], acc);
        }
      }
      binrow[pw] = acc;
    }
    float rm[5];
    #pragma unroll
    for (int ox=0; ox<5; ++ox)
      rm[ox] = fmaxf(fmaxf(binrow[2*ox], binrow[2*ox+1]), binrow[2*ox+2]);
    if (ph == 0){
      #pragma unroll
      for (int ox=0; ox<5; ++ox) awin[ox] = rm[ox];
    } else if (ph & 1){
      #pragma unroll
      for (int ox=0; ox<5; ++ox) awin[ox] = fmaxf(awin[ox], rm[ox]);
    } else {
      int oy = (ph-2) >> 1;
      #pragma unroll
      for (int ox=0; ox<5; ++ox){
        s_out[t*25 + oy*5 + ox] = fmaxf(awin[ox], rm[ox]);
        awin[ox] = rm[ox];
      }
    }
  }
  __syncthreads();

  // coalesced fp32 store of this ROI's [512][5][5] block
  float4* dst = (float4*)(out + (size_t)r*(Cc*25));
  const float4* src = (const float4*)s_out;
  for (int k=t; k<(Cc*25)/4; k+=512) dst[k]=src[k];
}

extern "C" void kernel_launch(void* const* d_in, const int* in_sizes, int n_in,
                              void* d_out, int out_size, void* d_ws, size_t ws_size,
                              hipStream_t stream)
{
  (void)d_ws; (void)ws_size; (void)in_sizes; (void)n_in; (void)out_size;
  roi_align_max_kernel<<<Rr, 512, 0, stream>>>((const float*)d_in[0],
                                               (const float*)d_in[1],
                                               (float*)d_out);
}

// Round 5
// 720.824 us; speedup vs baseline: 6.0610x; 6.0610x over previous
//
#include <hip/hip_runtime.h>
#include <stdint.h>

typedef unsigned short u16;
typedef unsigned int   u32;

#define Bn 4
#define Cc 512
#define Hh 96
#define Ww 96
#define HWc (Hh*Ww)   // 9216
#define AH 11
#define Rr 512
#define CP (Cc/2)     // 256 channel pairs (dwords per point in NHWC bf16)

__device__ __forceinline__ u16 f2bf(float f){
  u32 u = __float_as_uint(f);
  u += 0x7fffu + ((u>>16)&1u);
  return (u16)(u>>16);
}

// ---------- fp32 NCHW -> bf16 NHWC transpose (64x64 LDS tile) ----------
__global__ __launch_bounds__(256)
void transpose_kernel(const float* __restrict__ in, u32* __restrict__ out){
  __shared__ u16 tile[64][66];
  const int t = threadIdx.x;
  const int hw0 = blockIdx.x*64, c0 = blockIdx.y*64, b = blockIdx.z;
  {
    const int hwl = t & 63, cb = t >> 6;            // 4 c-rows per pass
    const float* ib = in + ((size_t)(b*Cc + c0))*HWc + hw0;
    #pragma unroll
    for (int p=0;p<16;++p){
      int cl = cb + p*4;
      tile[cl][hwl] = f2bf(ib[(size_t)cl*HWc + hwl]);
    }
  }
  __syncthreads();
  {
    const int cp = t & 31, hwb = t >> 5;            // 8 hw rows per pass
    u32* ob = out + ((size_t)b*HWc + hw0)*CP + (c0>>1);
    #pragma unroll
    for (int p=0;p<8;++p){
      int hw = hwb + p*8;
      u32 lo = tile[2*cp  ][hw];
      u32 hi = tile[2*cp+1][hw];
      ob[(size_t)hw*CP + cp] = lo | (hi<<16);
    }
  }
}

// ---------- fused RoIAlignAda + 3x3/s2 maxpool, NHWC bf16 input ----------
// one block per ROI; 256 threads; thread t owns channels 2t, 2t+1
__global__ __launch_bounds__(256)
void roi_align_max_nhwc(const u32* __restrict__ feat,
                        const float* __restrict__ rois,
                        float* __restrict__ out)
{
  __shared__ int   s_roff[AH][6];
  __shared__ float s_rw  [AH][6];
  __shared__ int   s_coff[AH][6];
  __shared__ float s_cw  [AH][6];
  __shared__ int   s_b;
  __shared__ __align__(16) float s_out[Cc*25];   // 51200 B

  const int t = threadIdx.x;
  const int r = blockIdx.x;

  if (t < AH*6){
    ((float*)s_rw)[t] = 0.0f;  ((int*)s_roff)[t] = 0;
    ((float*)s_cw)[t] = 0.0f;  ((int*)s_coff)[t] = 0;
  }
  if (t == 0){
    int b = (int)rois[r*5+0];
    s_b = min(max(b, 0), Bn-1);
  }
  __syncthreads();

  // geometry: threads 0..10 -> rows (ph), threads 64..74 -> cols (pw)
  if (t < AH || (t >= 64 && t < 64+AH)){
    const bool isrow = (t < AH);
    const int  p = isrow ? t : t-64;
    const float* rp = rois + r*5;
    const float c1 = rp[isrow?2:1], c2 = rp[isrow?4:3];
    // replicate np float32 ops exactly (no fp contraction at validity boundaries)
    float lo  = __fmul_rn(c1, 0.125f);
    float hi  = __fmul_rn(c2, 0.125f);
    float ext = fmaxf(__fsub_rn(hi,lo), 0.0f);
    float bin = __fdiv_rn(ext, 10.0f);
    float ctr = __fadd_rn(lo, __fmul_rn((float)p, bin));
    float strd = fmaxf(1.0f, rintf(__fdiv_rn(bin, 3.0f)));   // half-even == jnp.round
    bool ok = (ctr >= 0.0f) && (ctr < 96.0f);
    int rws[6]; float wts[6]; int nv=0;
    #pragma unroll
    for (int s=0;s<3;++s){
      float cc = __fadd_rn(ctr, __fmul_rn((float)(s-1), strd));
      bool v = (cc >= 0.0f) && (cc < 96.0f);
      float fl = fminf(fmaxf(floorf(cc),0.0f),94.0f);
      float fr = __fsub_rn(cc, fl);
      int ri = (int)fl;
      rws[2*s]=ri; rws[2*s+1]=ri+1;
      wts[2*s]  = v ? __fsub_rn(1.0f,fr) : 0.0f;
      wts[2*s+1]= v ? fr : 0.0f;
      nv += v?1:0;
    }
    float sc = ok ? (1.0f/(float)nv) : 0.0f;   // folds center_ok + 1/cnt (separable)
    int cr[6]; float cw[6]; int n=0;
    for (int k=0;k<6;++k){
      float wk=wts[k]; if (wk==0.0f) continue;
      if (n>0 && cr[n-1]==rws[k]) cw[n-1]+=wk;
      else { cr[n]=rws[k]; cw[n]=wk; ++n; }
    }
    const int mul = isrow ? (Ww*CP) : CP;      // offsets in dwords
    for (int k=0;k<n;++k){
      int off = cr[k]*mul;
      float wv = cw[k]*sc;
      if (isrow){ s_roff[p][k]=off; s_rw[p][k]=wv; }
      else      { s_coff[p][k]=off; s_cw[p][k]=wv; }
    }
  }
  __syncthreads();

  const u32* fb = feat + (size_t)s_b*((size_t)HWc*CP) + t;   // lane-coalesced base

  float2 awin[5];
  for (int ph=0; ph<AH; ++ph){
    float2 binrow[AH];
    #pragma unroll
    for (int pw=0; pw<AH; ++pw){
      float ax=0.0f, ay=0.0f;
      #pragma unroll
      for (int ai=0; ai<6; ++ai){
        float ra = s_rw[ph][ai];
        if (ra == 0.0f) continue;          // block-uniform skip
        int ro = s_roff[ph][ai];
        #pragma unroll
        for (int bi=0; bi<6; ++bi){
          float cb = s_cw[pw][bi];
          if (cb == 0.0f) continue;
          float w = ra*cb;
          u32 v = fb[ro + s_coff[pw][bi]];
          ax = fmaf(w, __uint_as_float(v<<16),           ax);
          ay = fmaf(w, __uint_as_float(v & 0xffff0000u), ay);
        }
      }
      binrow[pw] = make_float2(ax, ay);
    }
    float2 rm[5];
    #pragma unroll
    for (int ox=0; ox<5; ++ox){
      rm[ox].x = fmaxf(fmaxf(binrow[2*ox].x, binrow[2*ox+1].x), binrow[2*ox+2].x);
      rm[ox].y = fmaxf(fmaxf(binrow[2*ox].y, binrow[2*ox+1].y), binrow[2*ox+2].y);
    }
    if (ph == 0){
      #pragma unroll
      for (int ox=0; ox<5; ++ox) awin[ox] = rm[ox];
    } else if (ph & 1){
      #pragma unroll
      for (int ox=0; ox<5; ++ox){
        awin[ox].x = fmaxf(awin[ox].x, rm[ox].x);
        awin[ox].y = fmaxf(awin[ox].y, rm[ox].y);
      }
    } else {
      int oy = (ph-2) >> 1;
      #pragma unroll
      for (int ox=0; ox<5; ++ox){
        s_out[(2*t  )*25 + oy*5 + ox] = fmaxf(awin[ox].x, rm[ox].x);
        s_out[(2*t+1)*25 + oy*5 + ox] = fmaxf(awin[ox].y, rm[ox].y);
        awin[ox] = rm[ox];
      }
    }
  }
  __syncthreads();

  float* dst = out + (size_t)r*(Cc*25);
  for (int k=t; k<Cc*25; k+=256) dst[k] = s_out[k];
}

// ---------- fallback: round-4 NCHW fp32 direct (known-correct) ----------
__global__ __launch_bounds__(512, 1)
void roi_align_max_nchw(const float* __restrict__ feat,
                        const float* __restrict__ rois,
                        float* __restrict__ out)
{
  __shared__ int   s_roff[AH][6];
  __shared__ float s_rw  [AH][6];
  __shared__ int   s_coff[AH][6];
  __shared__ float s_cw  [AH][6];
  __shared__ int   s_b;
  __shared__ __align__(16) float s_out[Cc*25];

  const int t = threadIdx.x;
  const int r = blockIdx.x;

  if (t < AH*6){
    ((float*)s_rw)[t] = 0.0f;  ((int*)s_roff)[t] = 0;
    ((float*)s_cw)[t] = 0.0f;  ((int*)s_coff)[t] = 0;
  }
  if (t == 0){
    int b = (int)rois[r*5+0];
    s_b = min(max(b, 0), Bn-1);
  }
  __syncthreads();

  if (t < AH || (t >= 64 && t < 64+AH)){
    const bool isrow = (t < AH);
    const int  p = isrow ? t : t-64;
    const float* rp = rois + r*5;
    const float c1 = rp[isrow?2:1], c2 = rp[isrow?4:3];
    float lo  = __fmul_rn(c1, 0.125f);
    float hi  = __fmul_rn(c2, 0.125f);
    float ext = fmaxf(__fsub_rn(hi,lo), 0.0f);
    float bin = __fdiv_rn(ext, 10.0f);
    float ctr = __fadd_rn(lo, __fmul_rn((float)p, bin));
    float strd = fmaxf(1.0f, rintf(__fdiv_rn(bin, 3.0f)));
    bool ok = (ctr >= 0.0f) && (ctr < 96.0f);
    int rws[6]; float wts[6]; int nv=0;
    #pragma unroll
    for (int s=0;s<3;++s){
      float cc = __fadd_rn(ctr, __fmul_rn((float)(s-1), strd));
      bool v = (cc >= 0.0f) && (cc < 96.0f);
      float fl = fminf(fmaxf(floorf(cc),0.0f),94.0f);
      float fr = __fsub_rn(cc, fl);
      int ri = (int)fl;
      rws[2*s]=ri; rws[2*s+1]=ri+1;
      wts[2*s]  = v ? __fsub_rn(1.0f,fr) : 0.0f;
      wts[2*s+1]= v ? fr : 0.0f;
      nv += v?1:0;
    }
    float sc = ok ? (1.0f/(float)nv) : 0.0f;
    int cr[6]; float cw[6]; int n=0;
    for (int k=0;k<6;++k){
      float wk=wts[k]; if (wk==0.0f) continue;
      if (n>0 && cr[n-1]==rws[k]) cw[n-1]+=wk;
      else { cr[n]=rws[k]; cw[n]=wk; ++n; }
    }
    const int mul = isrow ? Ww : 1;
    for (int k=0;k<n;++k){
      int off = cr[k]*mul;
      float wv = cw[k]*sc;
      if (isrow){ s_roff[p][k]=off; s_rw[p][k]=wv; }
      else      { s_coff[p][k]=off; s_cw[p][k]=wv; }
    }
  }
  __syncthreads();

  const float* f0 = feat + ((size_t)s_b*Cc + t)*HWc;
  float awin[5];
  for (int ph=0; ph<AH; ++ph){
    float binrow[AH];
    #pragma unroll
    for (int pw=0; pw<AH; ++pw){
      float acc = 0.0f;
      #pragma unroll
      for (int ai=0; ai<6; ++ai){
        float ra = s_rw[ph][ai];
        if (ra == 0.0f) continue;
        int ro = s_roff[ph][ai];
        #pragma unroll
        for (int bi=0; bi<6; ++bi){
          float cb = s_cw[pw][bi];
          if (cb == 0.0f) continue;
          acc = fmaf(ra*cb, f0[ro + s_coff[pw][bi]], acc);
        }
      }
      binrow[pw] = acc;
    }
    float rm[5];
    #pragma unroll
    for (int ox=0; ox<5; ++ox)
      rm[ox] = fmaxf(fmaxf(binrow[2*ox], binrow[2*ox+1]), binrow[2*ox+2]);
    if (ph == 0){
      #pragma unroll
      for (int ox=0; ox<5; ++ox) awin[ox] = rm[ox];
    } else if (ph & 1){
      #pragma unroll
      for (int ox=0; ox<5; ++ox) awin[ox] = fmaxf(awin[ox], rm[ox]);
    } else {
      int oy = (ph-2) >> 1;
      #pragma unroll
      for (int ox=0; ox<5; ++ox){
        s_out[t*25 + oy*5 + ox] = fmaxf(awin[ox], rm[ox]);
        awin[ox] = rm[ox];
      }
    }
  }
  __syncthreads();

  float4* dst = (float4*)(out + (size_t)r*(Cc*25));
  const float4* src = (const float4*)s_out;
  for (int k=t; k<(Cc*25)/4; k+=512) dst[k]=src[k];
}

extern "C" void kernel_launch(void* const* d_in, const int* in_sizes, int n_in,
                              void* d_out, int out_size, void* d_ws, size_t ws_size,
                              hipStream_t stream)
{
  (void)in_sizes; (void)n_in; (void)out_size;
  const float* feat = (const float*)d_in[0];
  const float* rois = (const float*)d_in[1];
  float* out = (float*)d_out;
  const size_t need = (size_t)Bn*HWc*Cc*sizeof(u16);   // 37.75 MB bf16 NHWC
  if (ws_size >= need){
    u32* ws = (u32*)d_ws;
    dim3 g(HWc/64, Cc/64, Bn);
    transpose_kernel<<<g, 256, 0, stream>>>(feat, ws);
    roi_align_max_nhwc<<<Rr, 256, 0, stream>>>(ws, rois, out);
  } else {
    roi_align_max_nchw<<<Rr, 512, 0, stream>>>(feat, rois, out);
  }
}

// Round 6
// 196.134 us; speedup vs baseline: 22.2753x; 3.6752x over previous
//
#include <hip/hip_runtime.h>
#include <stdint.h>

typedef unsigned short u16;
typedef unsigned int   u32;

#define Bn 4
#define Cc 512
#define Hh 96
#define Ww 96
#define HWc (Hh*Ww)   // 9216
#define AH 11
#define Rr 512
#define CP (Cc/2)     // 256 dwords per point (bf16 NHWC)

__device__ __forceinline__ u16 f2bf(float f){
  u32 u = __float_as_uint(f);
  u += 0x7fffu + ((u>>16)&1u);
  return (u16)(u>>16);
}

// ---------- fp32 NCHW -> bf16 NHWC transpose (64x64 tile, float4 reads) ----------
__global__ __launch_bounds__(256)
void transpose_kernel(const float* __restrict__ in, u32* __restrict__ out){
  __shared__ u16 tile[64][66];
  const int t = threadIdx.x;
  const int hw0 = blockIdx.x*64, c0 = blockIdx.y*64, b = blockIdx.z;
  {
    const int hwq = (t & 15)*4, cl0 = t >> 4;       // 16 c-rows per pass
    const float* ib = in + ((size_t)(b*Cc + c0))*HWc + hw0;
    #pragma unroll
    for (int p=0;p<4;++p){
      int cl = cl0 + p*16;
      float4 v = *(const float4*)(ib + (size_t)cl*HWc + hwq);
      tile[cl][hwq+0] = f2bf(v.x);
      tile[cl][hwq+1] = f2bf(v.y);
      tile[cl][hwq+2] = f2bf(v.z);
      tile[cl][hwq+3] = f2bf(v.w);
    }
  }
  __syncthreads();
  {
    const int cp = t & 31, hwb = t >> 5;            // 8 hw rows per pass
    u32* ob = out + ((size_t)b*HWc + hw0)*CP + (c0>>1);
    #pragma unroll
    for (int p=0;p<8;++p){
      int hw = hwb + p*8;
      u32 lo = tile[2*cp  ][hw];
      u32 hi = tile[2*cp+1][hw];
      ob[(size_t)hw*CP + cp] = lo | (hi<<16);
    }
  }
}

// ---------- fused RoIAlignAda + 3x3/s2 maxpool, NHWC bf16, split 2 segs/ROI ----------
// grid 1024: r = bid>>1, seg = bid&1 (seg0: ph 0..4 -> oy 0..1; seg1: ph 4..10 -> oy 2..4)
// 256 threads; thread t owns channels 2t, 2t+1 (one dword per sample point)

template<int LO, int NPH, int NOY>
__device__ __forceinline__ void roi_seg_body(
    const u32* __restrict__ fb,
    const int   (*s_roff4)[4], const float (*s_rw4)[4],
    const int   (*s_coff4)[4], const float (*s_cw4)[4],
    float* __restrict__ s_out, int t)
{
  float2 awin[5];
  #pragma unroll 1
  for (int lp=0; lp<NPH; ++lp){
    const int ph = LO + lp;
    const int4   ro4 = *(const int4*)  s_roff4[ph];
    const float4 rw4 = *(const float4*)s_rw4[ph];
    const int   ro_[4] = {ro4.x, ro4.y, ro4.z, ro4.w};
    const float rw_[4] = {rw4.x, rw4.y, rw4.z, rw4.w};
    float2 binr[AH];
    #pragma unroll
    for (int pw=0; pw<AH; ++pw){
      const int4   co4 = *(const int4*)  s_coff4[pw];
      const float4 cw4 = *(const float4*)s_cw4[pw];
      const int   co_[4] = {co4.x, co4.y, co4.z, co4.w};
      const float cw_[4] = {cw4.x, cw4.y, cw4.z, cw4.w};
      u32 v[16];
      #pragma unroll
      for (int i=0;i<4;++i)
        #pragma unroll
        for (int j=0;j<4;++j)
          v[i*4+j] = fb[ro_[i] + co_[j]];      // 16 unconditional, batched loads
      float ax=0.0f, ay=0.0f;
      #pragma unroll
      for (int i=0;i<4;++i)
        #pragma unroll
        for (int j=0;j<4;++j){
          float w = rw_[i]*cw_[j];
          u32 d = v[i*4+j];
          ax = fmaf(w, __uint_as_float(d<<16),           ax);
          ay = fmaf(w, __uint_as_float(d & 0xffff0000u), ay);
        }
      binr[pw] = make_float2(ax, ay);
    }
    float2 rm[5];
    #pragma unroll
    for (int ox=0; ox<5; ++ox){
      rm[ox].x = fmaxf(fmaxf(binr[2*ox].x, binr[2*ox+1].x), binr[2*ox+2].x);
      rm[ox].y = fmaxf(fmaxf(binr[2*ox].y, binr[2*ox+1].y), binr[2*ox+2].y);
    }
    if (lp == 0){
      #pragma unroll
      for (int ox=0; ox<5; ++ox) awin[ox] = rm[ox];
    } else if (lp & 1){
      #pragma unroll
      for (int ox=0; ox<5; ++ox){
        awin[ox].x = fmaxf(awin[ox].x, rm[ox].x);
        awin[ox].y = fmaxf(awin[ox].y, rm[ox].y);
      }
    } else {
      const int ol = (lp-2) >> 1;
      #pragma unroll
      for (int ox=0; ox<5; ++ox){
        s_out[(2*t  )*(NOY*5) + ol*5 + ox] = fmaxf(awin[ox].x, rm[ox].x);
        s_out[(2*t+1)*(NOY*5) + ol*5 + ox] = fmaxf(awin[ox].y, rm[ox].y);
        awin[ox] = rm[ox];
      }
    }
  }
}

__global__ __launch_bounds__(256)
void roi_align_max_nhwc(const u32* __restrict__ feat,
                        const float* __restrict__ rois,
                        float* __restrict__ out)
{
  __shared__ __align__(16) int   s_roff4[AH][4];
  __shared__ __align__(16) float s_rw4  [AH][4];
  __shared__ __align__(16) int   s_coff4[AH][4];
  __shared__ __align__(16) float s_cw4  [AH][4];
  __shared__ int s_b;
  __shared__ __align__(16) float s_out[Cc*15];   // 30720 B (seg1 uses all, seg0 2/3)

  const int t   = threadIdx.x;
  const int r   = blockIdx.x >> 1;
  const int seg = blockIdx.x & 1;

  if (t == 0){
    int b = (int)rois[r*5+0];
    s_b = min(max(b, 0), Bn-1);
  }

  // geometry: threads 0..10 -> rows (ph), threads 64..74 -> cols (pw)
  if (t < AH || (t >= 64 && t < 64+AH)){
    const bool isrow = (t < AH);
    const int  p = isrow ? t : t-64;
    const float* rp = rois + r*5;
    const float c1 = rp[isrow?2:1], c2 = rp[isrow?4:3];
    // replicate np float32 ops exactly (no fp contraction at validity boundaries)
    float lo  = __fmul_rn(c1, 0.125f);
    float hi  = __fmul_rn(c2, 0.125f);
    float ext = fmaxf(__fsub_rn(hi,lo), 0.0f);
    float bin = __fdiv_rn(ext, 10.0f);
    float ctr = __fadd_rn(lo, __fmul_rn((float)p, bin));
    float strd = fmaxf(1.0f, rintf(__fdiv_rn(bin, 3.0f)));   // half-even == jnp.round
    bool ok = (ctr >= 0.0f) && (ctr < 96.0f);
    int rws[6]; float wts[6]; int nv=0;
    #pragma unroll
    for (int s=0;s<3;++s){
      float cc = __fadd_rn(ctr, __fmul_rn((float)(s-1), strd));
      bool vv = (cc >= 0.0f) && (cc < 96.0f);
      float fl = fminf(fmaxf(floorf(cc),0.0f),94.0f);
      float fr = __fsub_rn(cc, fl);
      int ri = (int)fl;
      rws[2*s]=ri; rws[2*s+1]=ri+1;
      wts[2*s]  = vv ? __fsub_rn(1.0f,fr) : 0.0f;
      wts[2*s+1]= vv ? fr : 0.0f;
      nv += vv?1:0;
    }
    float sc = ok ? (1.0f/(float)nv) : 0.0f;   // folds center_ok + 1/cnt (separable)
    // full dedupe-merge; stride==1 for this data => <=4 unique rows. pad to 4.
    int cr[4]={0,0,0,0}; float cwv[4]={0.0f,0.0f,0.0f,0.0f}; int n=0;
    for (int k=0;k<6;++k){
      float wk=wts[k]; if (wk==0.0f) continue;
      int rr=rws[k]; bool fnd=false;
      for (int j=0;j<n;++j) if (cr[j]==rr){ cwv[j]+=wk; fnd=true; break; }
      if (!fnd && n<4){ cr[n]=rr; cwv[n]=wk; ++n; }
    }
    const int mul = isrow ? (Ww*CP) : CP;      // offsets in dwords
    #pragma unroll
    for (int k=0;k<4;++k){
      int off = cr[k]*mul;
      float wv = cwv[k]*sc;
      if (isrow){ s_roff4[p][k]=off; s_rw4[p][k]=wv; }
      else      { s_coff4[p][k]=off; s_cw4[p][k]=wv; }
    }
  }
  __syncthreads();

  const u32* fb = feat + (size_t)s_b*((size_t)HWc*CP) + t;   // lane-coalesced base

  if (seg == 0) roi_seg_body<0,5,2>(fb, s_roff4, s_rw4, s_coff4, s_cw4, s_out, t);
  else          roi_seg_body<4,7,3>(fb, s_roff4, s_rw4, s_coff4, s_cw4, s_out, t);
  __syncthreads();

  // coalesced-ish copy-out of this segment's [512][NOY][5] chunk
  if (seg == 0){
    float* dst = out + (size_t)r*(Cc*25);
    for (int k=t; k<Cc*10; k+=256){
      int c = k/10, j = k - c*10;
      dst[c*25 + j] = s_out[k];
    }
  } else {
    float* dst = out + (size_t)r*(Cc*25) + 10;
    for (int k=t; k<Cc*15; k+=256){
      int c = k/15, j = k - c*15;
      dst[c*25 + j] = s_out[k];
    }
  }
}

// ---------- fallback: NCHW fp32 direct (known-correct, used only if ws too small) ----------
__global__ __launch_bounds__(512, 1)
void roi_align_max_nchw(const float* __restrict__ feat,
                        const float* __restrict__ rois,
                        float* __restrict__ out)
{
  __shared__ int   s_roff[AH][6];
  __shared__ float s_rw  [AH][6];
  __shared__ int   s_coff[AH][6];
  __shared__ float s_cw  [AH][6];
  __shared__ int   s_b;
  __shared__ __align__(16) float s_out[Cc*25];

  const int t = threadIdx.x;
  const int r = blockIdx.x;

  if (t < AH*6){
    ((float*)s_rw)[t] = 0.0f;  ((int*)s_roff)[t] = 0;
    ((float*)s_cw)[t] = 0.0f;  ((int*)s_coff)[t] = 0;
  }
  if (t == 0){
    int b = (int)rois[r*5+0];
    s_b = min(max(b, 0), Bn-1);
  }
  __syncthreads();

  if (t < AH || (t >= 64 && t < 64+AH)){
    const bool isrow = (t < AH);
    const int  p = isrow ? t : t-64;
    const float* rp = rois + r*5;
    const float c1 = rp[isrow?2:1], c2 = rp[isrow?4:3];
    float lo  = __fmul_rn(c1, 0.125f);
    float hi  = __fmul_rn(c2, 0.125f);
    float ext = fmaxf(__fsub_rn(hi,lo), 0.0f);
    float bin = __fdiv_rn(ext, 10.0f);
    float ctr = __fadd_rn(lo, __fmul_rn((float)p, bin));
    float strd = fmaxf(1.0f, rintf(__fdiv_rn(bin, 3.0f)));
    bool ok = (ctr >= 0.0f) && (ctr < 96.0f);
    int rws[6]; float wts[6]; int nv=0;
    #pragma unroll
    for (int s=0;s<3;++s){
      float cc = __fadd_rn(ctr, __fmul_rn((float)(s-1), strd));
      bool vv = (cc >= 0.0f) && (cc < 96.0f);
      float fl = fminf(fmaxf(floorf(cc),0.0f),94.0f);
      float fr = __fsub_rn(cc, fl);
      int ri = (int)fl;
      rws[2*s]=ri; rws[2*s+1]=ri+1;
      wts[2*s]  = vv ? __fsub_rn(1.0f,fr) : 0.0f;
      wts[2*s+1]= vv ? fr : 0.0f;
      nv += vv?1:0;
    }
    float sc = ok ? (1.0f/(float)nv) : 0.0f;
    int cr[6]; float cw[6]; int n=0;
    for (int k=0;k<6;++k){
      float wk=wts[k]; if (wk==0.0f) continue;
      if (n>0 && cr[n-1]==rws[k]) cw[n-1]+=wk;
      else { cr[n]=rws[k]; cw[n]=wk; ++n; }
    }
    const int mul = isrow ? Ww : 1;
    for (int k=0;k<n;++k){
      int off = cr[k]*mul;
      float wv = cw[k]*sc;
      if (isrow){ s_roff[p][k]=off; s_rw[p][k]=wv; }
      else      { s_coff[p][k]=off; s_cw[p][k]=wv; }
    }
  }
  __syncthreads();

  const float* f0 = feat + ((size_t)s_b*Cc + t)*HWc;
  float awin[5];
  for (int ph=0; ph<AH; ++ph){
    float binrow[AH];
    #pragma unroll
    for (int pw=0; pw<AH; ++pw){
      float acc = 0.0f;
      #pragma unroll
      for (int ai=0; ai<6; ++ai){
        float ra = s_rw[ph][ai];
        if (ra == 0.0f) continue;
        int ro = s_roff[ph][ai];
        #pragma unroll
        for (int bi=0; bi<6; ++bi){
          float cb = s_cw[pw][bi];
          if (cb == 0.0f) continue;
          acc = fmaf(ra*cb, f0[ro + s_coff[pw][bi]], acc);
        }
      }
      binrow[pw] = acc;
    }
    float rm[5];
    #pragma unroll
    for (int ox=0; ox<5; ++ox)
      rm[ox] = fmaxf(fmaxf(binrow[2*ox], binrow[2*ox+1]), binrow[2*ox+2]);
    if (ph == 0){
      #pragma unroll
      for (int ox=0; ox<5; ++ox) awin[ox] = rm[ox];
    } else if (ph & 1){
      #pragma unroll
      for (int ox=0; ox<5; ++ox) awin[ox] = fmaxf(awin[ox], rm[ox]);
    } else {
      int oy = (ph-2) >> 1;
      #pragma unroll
      for (int ox=0; ox<5; ++ox){
        s_out[t*25 + oy*5 + ox] = fmaxf(awin[ox], rm[ox]);
        awin[ox] = rm[ox];
      }
    }
  }
  __syncthreads();

  float4* dst = (float4*)(out + (size_t)r*(Cc*25));
  const float4* src = (const float4*)s_out;
  for (int k=t; k<(Cc*25)/4; k+=512) dst[k]=src[k];
}

extern "C" void kernel_launch(void* const* d_in, const int* in_sizes, int n_in,
                              void* d_out, int out_size, void* d_ws, size_t ws_size,
                              hipStream_t stream)
{
  (void)in_sizes; (void)n_in; (void)out_size;
  const float* feat = (const float*)d_in[0];
  const float* rois = (const float*)d_in[1];
  float* out = (float*)d_out;
  const size_t need = (size_t)Bn*HWc*Cc*sizeof(u16);   // 37.75 MB bf16 NHWC
  if (ws_size >= need){
    u32* ws = (u32*)d_ws;
    dim3 g(HWc/64, Cc/64, Bn);
    transpose_kernel<<<g, 256, 0, stream>>>(feat, ws);
    roi_align_max_nhwc<<<Rr*2, 256, 0, stream>>>(ws, rois, out);
  } else {
    roi_align_max_nchw<<<Rr, 512, 0, stream>>>(feat, rois, out);
  }
}

// Round 7
// 176.900 us; speedup vs baseline: 24.6973x; 1.1087x over previous
//
#include <hip/hip_runtime.h>
#include <stdint.h>

typedef unsigned short u16;
typedef unsigned int   u32;

#define Bn 4
#define Cc 512
#define Hh 96
#define Ww 96
#define HWc (Hh*Ww)   // 9216
#define AH 11
#define Rr 512
#define CP (Cc/2)     // 256 dwords per point (bf16 NHWC)

__device__ __forceinline__ u16 f2bf(float f){
  u32 u = __float_as_uint(f);
  u += 0x7fffu + ((u>>16)&1u);
  return (u16)(u>>16);
}

// ---- fp32 NCHW -> bf16-pair (u32) NHWC transpose; 128hw x 128c tile ----
// LDS tile: u32 tile[hw_local 128][cp_local 64 +1 pad]  (33.3 KB)
__global__ __launch_bounds__(256)
void transpose_kernel(const float* __restrict__ in, u32* __restrict__ out){
  __shared__ u32 tile[128][65];
  const int t = threadIdx.x;
  const int hw0 = blockIdx.x*128, c0 = blockIdx.y*128, b = blockIdx.z;
  {
    const int q   = t & 31;        // hw quad: covers hw_local 4q..4q+3
    const int cp0 = t >> 5;        // 0..7
    const float* ib = in + ((size_t)(b*Cc + c0))*HWc + hw0 + 4*q;
    #pragma unroll
    for (int p=0;p<8;++p){
      const int cp = cp0 + p*8;    // 0..63 channel pair within tile
      const float* pa = ib + (size_t)(2*cp)*HWc;
      float4 A = *(const float4*)pa;
      float4 B = *(const float4*)(pa + HWc);
      tile[4*q+0][cp] = (u32)f2bf(A.x) | ((u32)f2bf(B.x)<<16);
      tile[4*q+1][cp] = (u32)f2bf(A.y) | ((u32)f2bf(B.y)<<16);
      tile[4*q+2][cp] = (u32)f2bf(A.z) | ((u32)f2bf(B.z)<<16);
      tile[4*q+3][cp] = (u32)f2bf(A.w) | ((u32)f2bf(B.w)<<16);
    }
  }
  __syncthreads();
  {
    const int l = t & 63, wv = t >> 6;     // lane covers one cp, wave covers a row
    u32* ob = out + ((size_t)b*HWc + hw0)*CP + (c0>>1) + l;
    #pragma unroll
    for (int k=0;k<32;++k){
      const int hw = wv*32 + k;
      ob[(size_t)hw*CP] = tile[hw][l];     // 64 lanes -> 256B contiguous
    }
  }
}

// ---- fused RoIAlignAda + 3x3/s2 maxpool, NHWC bf16, channel-split 2 ----
// grid 1024: r = bid>>1, half = bid&1 (dwords half*128 .. half*128+127)
// 128 threads; thread t owns channels 2*(half*128+t), +1
__global__ __launch_bounds__(128)
void roi_align_max_nhwc(const u32* __restrict__ feat,
                        const float* __restrict__ rois,
                        float* __restrict__ out)
{
  __shared__ __align__(16) int4   s_ro[AH];
  __shared__ __align__(16) float4 s_rw[AH];
  __shared__ __align__(16) int4   s_co[AH];
  __shared__ __align__(16) float4 s_cw[AH];
  __shared__ int s_b;
  __shared__ __align__(16) float s_out[256*25];   // 25.6 KB

  const int t    = threadIdx.x;
  const int r    = blockIdx.x >> 1;
  const int half = blockIdx.x & 1;

  if (t == 0){
    int b = (int)rois[r*5+0];
    s_b = min(max(b, 0), Bn-1);
  }

  // geometry: threads 0..10 -> rows (ph), threads 64..74 -> cols (pw)
  if (t < AH || (t >= 64 && t < 64+AH)){
    const bool isrow = (t < AH);
    const int  p = isrow ? t : t-64;
    const float* rp = rois + r*5;
    const float c1 = rp[isrow?2:1], c2 = rp[isrow?4:3];
    // replicate np float32 ops exactly (no fp contraction at validity boundaries)
    float lo  = __fmul_rn(c1, 0.125f);
    float hi  = __fmul_rn(c2, 0.125f);
    float ext = fmaxf(__fsub_rn(hi,lo), 0.0f);
    float bin = __fdiv_rn(ext, 10.0f);
    float ctr = __fadd_rn(lo, __fmul_rn((float)p, bin));
    float strd = fmaxf(1.0f, rintf(__fdiv_rn(bin, 3.0f)));   // half-even == jnp.round
    bool ok = (ctr >= 0.0f) && (ctr < 96.0f);
    int rws[6]; float wts[6]; int nv=0;
    #pragma unroll
    for (int s=0;s<3;++s){
      float cc = __fadd_rn(ctr, __fmul_rn((float)(s-1), strd));
      bool vv = (cc >= 0.0f) && (cc < 96.0f);
      float fl = fminf(fmaxf(floorf(cc),0.0f),94.0f);
      float fr = __fsub_rn(cc, fl);
      int ri = (int)fl;
      rws[2*s]=ri; rws[2*s+1]=ri+1;
      wts[2*s]  = vv ? __fsub_rn(1.0f,fr) : 0.0f;
      wts[2*s+1]= vv ? fr : 0.0f;
      nv += vv?1:0;
    }
    float sc = ok ? (1.0f/(float)nv) : 0.0f;   // folds center_ok + 1/cnt (separable)
    // dedupe-merge (stride==1 here => <=4 unique), pad to 4 with w=0
    int cr[4]={0,0,0,0}; float cwv[4]={0.0f,0.0f,0.0f,0.0f}; int n=0;
    for (int k=0;k<6;++k){
      float wk=wts[k]; if (wk==0.0f) continue;
      int rr=rws[k]; bool fnd=false;
      for (int j=0;j<n;++j) if (cr[j]==rr){ cwv[j]+=wk; fnd=true; break; }
      if (!fnd && n<4){ cr[n]=rr; cwv[n]=wk; ++n; }
    }
    const int mul = isrow ? (Ww*CP) : CP;      // offsets in dwords
    if (isrow){
      s_ro[p] = make_int4(cr[0]*mul, cr[1]*mul, cr[2]*mul, cr[3]*mul);
      s_rw[p] = make_float4(cwv[0]*sc, cwv[1]*sc, cwv[2]*sc, cwv[3]*sc);
    } else {
      s_co[p] = make_int4(cr[0]*mul, cr[1]*mul, cr[2]*mul, cr[3]*mul);
      s_cw[p] = make_float4(cwv[0]*sc, cwv[1]*sc, cwv[2]*sc, cwv[3]*sc);
    }
  }
  __syncthreads();

  const u32* fbase = feat + (size_t)s_b*((size_t)HWc*CP);
  const int tb = half*128 + t;                 // this thread's dword lane

  // hoist column voffsets + weights into registers (per-bin addr VALU ~0)
  int   vo[AH][4]; float cwr[AH][4];
  #pragma unroll
  for (int pw=0; pw<AH; ++pw){
    int4 c4 = s_co[pw]; float4 w4 = s_cw[pw];
    vo[pw][0]=tb+c4.x; vo[pw][1]=tb+c4.y; vo[pw][2]=tb+c4.z; vo[pw][3]=tb+c4.w;
    cwr[pw][0]=w4.x; cwr[pw][1]=w4.y; cwr[pw][2]=w4.z; cwr[pw][3]=w4.w;
  }

  float2 awin[5];
  #pragma unroll 1
  for (int ph=0; ph<AH; ++ph){
    int4   r4 = s_ro[ph];
    float4 w4 = s_rw[ph];
    // scalar row bases (SGPR-pair addressing for the gathers)
    const u32* r0 = fbase + __builtin_amdgcn_readfirstlane(r4.x);
    const u32* r1 = fbase + __builtin_amdgcn_readfirstlane(r4.y);
    const u32* r2 = fbase + __builtin_amdgcn_readfirstlane(r4.z);
    const u32* r3 = fbase + __builtin_amdgcn_readfirstlane(r4.w);
    const float rw_[4] = {w4.x, w4.y, w4.z, w4.w};
    float2 binr[AH];
    #pragma unroll
    for (int pw=0; pw<AH; ++pw){
      u32 v[16];
      #pragma unroll
      for (int j=0;j<4;++j){
        v[0*4+j] = r0[vo[pw][j]];
        v[1*4+j] = r1[vo[pw][j]];
        v[2*4+j] = r2[vo[pw][j]];
        v[3*4+j] = r3[vo[pw][j]];
      }
      float ax=0.0f, ay=0.0f;
      #pragma unroll
      for (int i=0;i<4;++i)
        #pragma unroll
        for (int j=0;j<4;++j){
          float w = rw_[i]*cwr[pw][j];
          u32 d = v[i*4+j];
          ax = fmaf(w, __uint_as_float(d<<16),           ax);
          ay = fmaf(w, __uint_as_float(d & 0xffff0000u), ay);
        }
      binr[pw] = make_float2(ax, ay);
    }
    float2 rm[5];
    #pragma unroll
    for (int ox=0; ox<5; ++ox){
      rm[ox].x = fmaxf(fmaxf(binr[2*ox].x, binr[2*ox+1].x), binr[2*ox+2].x);
      rm[ox].y = fmaxf(fmaxf(binr[2*ox].y, binr[2*ox+1].y), binr[2*ox+2].y);
    }
    if (ph == 0){
      #pragma unroll
      for (int ox=0; ox<5; ++ox) awin[ox] = rm[ox];
    } else if (ph & 1){
      #pragma unroll
      for (int ox=0; ox<5; ++ox){
        awin[ox].x = fmaxf(awin[ox].x, rm[ox].x);
        awin[ox].y = fmaxf(awin[ox].y, rm[ox].y);
      }
    } else {
      const int oy = (ph-2) >> 1;
      #pragma unroll
      for (int ox=0; ox<5; ++ox){
        s_out[(2*t  )*25 + oy*5 + ox] = fmaxf(awin[ox].x, rm[ox].x);
        s_out[(2*t+1)*25 + oy*5 + ox] = fmaxf(awin[ox].y, rm[ox].y);
        awin[ox] = rm[ox];
      }
    }
  }
  __syncthreads();

  // coalesced float4 store of this half's [256][5][5] chunk
  float4* dst = (float4*)(out + (size_t)r*(Cc*25) + half*(256*25));
  const float4* src = (const float4*)s_out;
  for (int k=t; k<(256*25)/4; k+=128) dst[k]=src[k];
}

// ---- fallback: NCHW fp32 direct (known-correct, used only if ws too small) ----
__global__ __launch_bounds__(512, 1)
void roi_align_max_nchw(const float* __restrict__ feat,
                        const float* __restrict__ rois,
                        float* __restrict__ out)
{
  __shared__ int   s_roff[AH][6];
  __shared__ float s_rw  [AH][6];
  __shared__ int   s_coff[AH][6];
  __shared__ float s_cw  [AH][6];
  __shared__ int   s_b;
  __shared__ __align__(16) float s_out[Cc*25];

  const int t = threadIdx.x;
  const int r = blockIdx.x;

  if (t < AH*6){
    ((float*)s_rw)[t] = 0.0f;  ((int*)s_roff)[t] = 0;
    ((float*)s_cw)[t] = 0.0f;  ((int*)s_coff)[t] = 0;
  }
  if (t == 0){
    int b = (int)rois[r*5+0];
    s_b = min(max(b, 0), Bn-1);
  }
  __syncthreads();

  if (t < AH || (t >= 64 && t < 64+AH)){
    const bool isrow = (t < AH);
    const int  p = isrow ? t : t-64;
    const float* rp = rois + r*5;
    const float c1 = rp[isrow?2:1], c2 = rp[isrow?4:3];
    float lo  = __fmul_rn(c1, 0.125f);
    float hi  = __fmul_rn(c2, 0.125f);
    float ext = fmaxf(__fsub_rn(hi,lo), 0.0f);
    float bin = __fdiv_rn(ext, 10.0f);
    float ctr = __fadd_rn(lo, __fmul_rn((float)p, bin));
    float strd = fmaxf(1.0f, rintf(__fdiv_rn(bin, 3.0f)));
    bool ok = (ctr >= 0.0f) && (ctr < 96.0f);
    int rws[6]; float wts[6]; int nv=0;
    #pragma unroll
    for (int s=0;s<3;++s){
      float cc = __fadd_rn(ctr, __fmul_rn((float)(s-1), strd));
      bool vv = (cc >= 0.0f) && (cc < 96.0f);
      float fl = fminf(fmaxf(floorf(cc),0.0f),94.0f);
      float fr = __fsub_rn(cc, fl);
      int ri = (int)fl;
      rws[2*s]=ri; rws[2*s+1]=ri+1;
      wts[2*s]  = vv ? __fsub_rn(1.0f,fr) : 0.0f;
      wts[2*s+1]= vv ? fr : 0.0f;
      nv += vv?1:0;
    }
    float sc = ok ? (1.0f/(float)nv) : 0.0f;
    int cr[6]; float cw[6]; int n=0;
    for (int k=0;k<6;++k){
      float wk=wts[k]; if (wk==0.0f) continue;
      if (n>0 && cr[n-1]==rws[k]) cw[n-1]+=wk;
      else { cr[n]=rws[k]; cw[n]=wk; ++n; }
    }
    const int mul = isrow ? Ww : 1;
    for (int k=0;k<n;++k){
      int off = cr[k]*mul;
      float wv = cw[k]*sc;
      if (isrow){ s_roff[p][k]=off; s_rw[p][k]=wv; }
      else      { s_coff[p][k]=off; s_cw[p][k]=wv; }
    }
  }
  __syncthreads();

  const float* f0 = feat + ((size_t)s_b*Cc + t)*HWc;
  float awin[5];
  for (int ph=0; ph<AH; ++ph){
    float binrow[AH];
    #pragma unroll
    for (int pw=0; pw<AH; ++pw){
      float acc = 0.0f;
      #pragma unroll
      for (int ai=0; ai<6; ++ai){
        float ra = s_rw[ph][ai];
        if (ra == 0.0f) continue;
        int ro = s_roff[ph][ai];
        #pragma unroll
        for (int bi=0; bi<6; ++bi){
          float cb = s_cw[pw][bi];
          if (cb == 0.0f) continue;
          acc = fmaf(ra*cb, f0[ro + s_coff[pw][bi]], acc);
        }
      }
      binrow[pw] = acc;
    }
    float rm[5];
    #pragma unroll
    for (int ox=0; ox<5; ++ox)
      rm[ox] = fmaxf(fmaxf(binrow[2*ox], binrow[2*ox+1]), binrow[2*ox+2]);
    if (ph == 0){
      #pragma unroll
      for (int ox=0; ox<5; ++ox) awin[ox] = rm[ox];
    } else if (ph & 1){
      #pragma unroll
      for (int ox=0; ox<5; ++ox) awin[ox] = fmaxf(awin[ox], rm[ox]);
    } else {
      int oy = (ph-2) >> 1;
      #pragma unroll
      for (int ox=0; ox<5; ++ox){
        s_out[t*25 + oy*5 + ox] = fmaxf(awin[ox], rm[ox]);
        awin[ox] = rm[ox];
      }
    }
  }
  __syncthreads();

  float4* dst = (float4*)(out + (size_t)r*(Cc*25));
  const float4* src = (const float4*)s_out;
  for (int k=t; k<(Cc*25)/4; k+=512) dst[k]=src[k];
}

extern "C" void kernel_launch(void* const* d_in, const int* in_sizes, int n_in,
                              void* d_out, int out_size, void* d_ws, size_t ws_size,
                              hipStream_t stream)
{
  (void)in_sizes; (void)n_in; (void)out_size;
  const float* feat = (const float*)d_in[0];
  const float* rois = (const float*)d_in[1];
  float* out = (float*)d_out;
  const size_t need = (size_t)Bn*HWc*Cc*sizeof(u16);   // 37.75 MB bf16 NHWC
  if (ws_size >= need){
    u32* ws = (u32*)d_ws;
    dim3 g(HWc/128, Cc/128, Bn);
    transpose_kernel<<<g, 256, 0, stream>>>(feat, ws);
    roi_align_max_nhwc<<<Rr*2, 128, 0, stream>>>(ws, rois, out);
  } else {
    roi_align_max_nchw<<<Rr, 512, 0, stream>>>(feat, rois, out);
  }
}

// Round 8
// 173.521 us; speedup vs baseline: 25.1782x; 1.0195x over previous
//
#include <hip/hip_runtime.h>
#include <stdint.h>

typedef unsigned short u16;
typedef unsigned int   u32;

#define Bn 4
#define Cc 512
#define Hh 96
#define Ww 96
#define HWc (Hh*Ww)   // 9216
#define AH 11
#define Rr 512
#define CP (Cc/2)     // 256 dwords per point (bf16 NHWC)

__device__ __forceinline__ u16 f2bf(float f){
  u32 u = __float_as_uint(f);
  u += 0x7fffu + ((u>>16)&1u);
  return (u16)(u>>16);
}
__device__ __forceinline__ u32 pk2(float a, float b){
  return (u32)f2bf(a) | ((u32)f2bf(b)<<16);
}

// ---- fp32 NCHW -> bf16-pair (u32) NHWC transpose; 128hw x 128c tile ----
// LDS: u32 tile[128*64], XOR-swizzled col' = cp ^ (hw>>2)  -> conflict-free
__global__ __launch_bounds__(256)
void transpose_kernel(const float* __restrict__ in, u32* __restrict__ out){
  __shared__ u32 tile[128*64];   // 32 KB
  const int t = threadIdx.x;
  const int hw0 = blockIdx.x*128, c0 = blockIdx.y*128, b = blockIdx.z;
  {
    const int q = t & 31, cp0 = t >> 5;           // q: hw quad, cp0: 0..7
    const float* ib = in + ((size_t)(b*Cc + c0))*HWc + hw0 + 4*q;
    #pragma unroll
    for (int p=0;p<8;++p){
      const int cp = cp0 + p*8;                   // 0..63 channel pair in tile
      const float* pa = ib + (size_t)(2*cp)*HWc;
      float4 A = *(const float4*)pa;
      float4 B = *(const float4*)(pa + HWc);
      const int cs = cp ^ q;                      // (4q+i)>>2 == q for i<4
      tile[(4*q+0)*64 + cs] = pk2(A.x,B.x);
      tile[(4*q+1)*64 + cs] = pk2(A.y,B.y);
      tile[(4*q+2)*64 + cs] = pk2(A.z,B.z);
      tile[(4*q+3)*64 + cs] = pk2(A.w,B.w);
    }
  }
  __syncthreads();
  {
    const int l = t & 63, wv = t >> 6;            // lane = cp, wave = row group
    u32* ob = out + ((size_t)b*HWc + hw0)*CP + (c0>>1) + l;
    #pragma unroll
    for (int k=0;k<32;++k){
      const int hw = wv*32 + k;
      ob[(size_t)hw*CP] = tile[hw*64 + (l ^ (hw>>2))];  // 256B contiguous store
    }
  }
}

// ---- fused RoIAlignAda + 3x3/s2 maxpool, NHWC bf16, channel-split 2 ----
// grid 1024: r = bid>>1, half = bid&1; 128 threads; thread t owns dword half*128+t
__global__ __launch_bounds__(128)
void roi_align_max_nhwc(const u32* __restrict__ feat,
                        const float* __restrict__ rois,
                        float* __restrict__ out)
{
  __shared__ __align__(16) int4   s_ro[AH];
  __shared__ __align__(16) float4 s_rw[AH];
  __shared__ __align__(16) int4   s_co[AH];
  __shared__ __align__(16) float4 s_cw[AH];
  __shared__ int s_b;
  __shared__ __align__(16) float s_out[256*25];   // 25.6 KB

  const int t    = threadIdx.x;
  const int r    = blockIdx.x >> 1;
  const int half = blockIdx.x & 1;

  if (t == 0){
    int b = (int)rois[r*5+0];
    s_b = min(max(b, 0), Bn-1);
  }

  // geometry: threads 0..10 -> rows (ph), threads 64..74 -> cols (pw)
  if (t < AH || (t >= 64 && t < 64+AH)){
    const bool isrow = (t < AH);
    const int  p = isrow ? t : t-64;
    const float* rp = rois + r*5;
    const float c1 = rp[isrow?2:1], c2 = rp[isrow?4:3];
    // replicate np float32 ops exactly (no fp contraction at validity boundaries)
    float lo  = __fmul_rn(c1, 0.125f);
    float hi  = __fmul_rn(c2, 0.125f);
    float ext = fmaxf(__fsub_rn(hi,lo), 0.0f);
    float bin = __fdiv_rn(ext, 10.0f);
    float ctr = __fadd_rn(lo, __fmul_rn((float)p, bin));
    float strd = fmaxf(1.0f, rintf(__fdiv_rn(bin, 3.0f)));   // half-even == jnp.round
    bool ok = (ctr >= 0.0f) && (ctr < 96.0f);
    int rws[6]; float wts[6]; int nv=0;
    #pragma unroll
    for (int s=0;s<3;++s){
      float cc = __fadd_rn(ctr, __fmul_rn((float)(s-1), strd));
      bool vv = (cc >= 0.0f) && (cc < 96.0f);
      float fl = fminf(fmaxf(floorf(cc),0.0f),94.0f);
      float fr = __fsub_rn(cc, fl);
      int ri = (int)fl;
      rws[2*s]=ri; rws[2*s+1]=ri+1;
      wts[2*s]  = vv ? __fsub_rn(1.0f,fr) : 0.0f;
      wts[2*s+1]= vv ? fr : 0.0f;
      nv += vv?1:0;
    }
    float sc = ok ? (1.0f/(float)nv) : 0.0f;   // folds center_ok + 1/cnt (separable)
    // dedupe-merge (stride==1 here => <=4 unique), pad to 4 with w=0
    int cr[4]={0,0,0,0}; float cwv[4]={0.0f,0.0f,0.0f,0.0f}; int n=0;
    for (int k=0;k<6;++k){
      float wk=wts[k]; if (wk==0.0f) continue;
      int rr=rws[k]; bool fnd=false;
      for (int j=0;j<n;++j) if (cr[j]==rr){ cwv[j]+=wk; fnd=true; break; }
      if (!fnd && n<4){ cr[n]=rr; cwv[n]=wk; ++n; }
    }
    const int mul = isrow ? (Ww*CP) : CP;      // offsets in dwords
    if (isrow){
      s_ro[p] = make_int4(cr[0]*mul, cr[1]*mul, cr[2]*mul, cr[3]*mul);
      s_rw[p] = make_float4(cwv[0]*sc, cwv[1]*sc, cwv[2]*sc, cwv[3]*sc);
    } else {
      s_co[p] = make_int4(cr[0]*mul, cr[1]*mul, cr[2]*mul, cr[3]*mul);
      s_cw[p] = make_float4(cwv[0]*sc, cwv[1]*sc, cwv[2]*sc, cwv[3]*sc);
    }
  }
  __syncthreads();

  const u32* fbase = feat + (size_t)s_b*((size_t)HWc*CP);
  const int tb = half*128 + t;                 // this thread's dword lane

  // hoist column voffsets + weights into registers
  int   vo[AH][4]; float cwr[AH][4];
  #pragma unroll
  for (int pw=0; pw<AH; ++pw){
    int4 c4 = s_co[pw]; float4 w4 = s_cw[pw];
    vo[pw][0]=tb+c4.x; vo[pw][1]=tb+c4.y; vo[pw][2]=tb+c4.z; vo[pw][3]=tb+c4.w;
    cwr[pw][0]=w4.x; cwr[pw][1]=w4.y; cwr[pw][2]=w4.z; cwr[pw][3]=w4.w;
  }

  float2 awin[5];
  #pragma unroll 1
  for (int ph=0; ph<AH; ++ph){
    int4   r4 = s_ro[ph];
    float4 w4 = s_rw[ph];
    // scalar row bases (SGPR-pair addressing for the gathers)
    const u32* r0 = fbase + __builtin_amdgcn_readfirstlane(r4.x);
    const u32* r1 = fbase + __builtin_amdgcn_readfirstlane(r4.y);
    const u32* r2 = fbase + __builtin_amdgcn_readfirstlane(r4.z);
    const u32* r3 = fbase + __builtin_amdgcn_readfirstlane(r4.w);
    const float rw_[4] = {w4.x, w4.y, w4.z, w4.w};
    float2 binr[AH];
    #pragma unroll
    for (int pw=0; pw<AH; ++pw){
      u32 v[16];
      #pragma unroll
      for (int j=0;j<4;++j){
        v[0*4+j] = r0[vo[pw][j]];
        v[1*4+j] = r1[vo[pw][j]];
        v[2*4+j] = r2[vo[pw][j]];
        v[3*4+j] = r3[vo[pw][j]];
      }
      // separable: column-combine per row, then row-combine (no weight muls)
      float ax=0.0f, ay=0.0f;
      #pragma unroll
      for (int i=0;i<4;++i){
        float cx=0.0f, cy=0.0f;
        #pragma unroll
        for (int j=0;j<4;++j){
          u32 d = v[i*4+j];
          cx = fmaf(cwr[pw][j], __uint_as_float(d<<16),           cx);
          cy = fmaf(cwr[pw][j], __uint_as_float(d & 0xffff0000u), cy);
        }
        ax = fmaf(rw_[i], cx, ax);
        ay = fmaf(rw_[i], cy, ay);
      }
      binr[pw] = make_float2(ax, ay);
    }
    float2 rm[5];
    #pragma unroll
    for (int ox=0; ox<5; ++ox){
      rm[ox].x = fmaxf(fmaxf(binr[2*ox].x, binr[2*ox+1].x), binr[2*ox+2].x);
      rm[ox].y = fmaxf(fmaxf(binr[2*ox].y, binr[2*ox+1].y), binr[2*ox+2].y);
    }
    if (ph == 0){
      #pragma unroll
      for (int ox=0; ox<5; ++ox) awin[ox] = rm[ox];
    } else if (ph & 1){
      #pragma unroll
      for (int ox=0; ox<5; ++ox){
        awin[ox].x = fmaxf(awin[ox].x, rm[ox].x);
        awin[ox].y = fmaxf(awin[ox].y, rm[ox].y);
      }
    } else {
      const int oy = (ph-2) >> 1;
      #pragma unroll
      for (int ox=0; ox<5; ++ox){
        s_out[(2*t  )*25 + oy*5 + ox] = fmaxf(awin[ox].x, rm[ox].x);
        s_out[(2*t+1)*25 + oy*5 + ox] = fmaxf(awin[ox].y, rm[ox].y);
        awin[ox] = rm[ox];
      }
    }
  }
  __syncthreads();

  // coalesced float4 store of this half's [256][5][5] chunk
  float4* dst = (float4*)(out + (size_t)r*(Cc*25) + half*(256*25));
  const float4* src = (const float4*)s_out;
  for (int k=t; k<(256*25)/4; k+=128) dst[k]=src[k];
}

// ---- fallback: NCHW fp32 direct (known-correct, used only if ws too small) ----
__global__ __launch_bounds__(512, 1)
void roi_align_max_nchw(const float* __restrict__ feat,
                        const float* __restrict__ rois,
                        float* __restrict__ out)
{
  __shared__ int   s_roff[AH][6];
  __shared__ float s_rw  [AH][6];
  __shared__ int   s_coff[AH][6];
  __shared__ float s_cw  [AH][6];
  __shared__ int   s_b;
  __shared__ __align__(16) float s_out[Cc*25];

  const int t = threadIdx.x;
  const int r = blockIdx.x;

  if (t < AH*6){
    ((float*)s_rw)[t] = 0.0f;  ((int*)s_roff)[t] = 0;
    ((float*)s_cw)[t] = 0.0f;  ((int*)s_coff)[t] = 0;
  }
  if (t == 0){
    int b = (int)rois[r*5+0];
    s_b = min(max(b, 0), Bn-1);
  }
  __syncthreads();

  if (t < AH || (t >= 64 && t < 64+AH)){
    const bool isrow = (t < AH);
    const int  p = isrow ? t : t-64;
    const float* rp = rois + r*5;
    const float c1 = rp[isrow?2:1], c2 = rp[isrow?4:3];
    float lo  = __fmul_rn(c1, 0.125f);
    float hi  = __fmul_rn(c2, 0.125f);
    float ext = fmaxf(__fsub_rn(hi,lo), 0.0f);
    float bin = __fdiv_rn(ext, 10.0f);
    float ctr = __fadd_rn(lo, __fmul_rn((float)p, bin));
    float strd = fmaxf(1.0f, rintf(__fdiv_rn(bin, 3.0f)));
    bool ok = (ctr >= 0.0f) && (ctr < 96.0f);
    int rws[6]; float wts[6]; int nv=0;
    #pragma unroll
    for (int s=0;s<3;++s){
      float cc = __fadd_rn(ctr, __fmul_rn((float)(s-1), strd));
      bool vv = (cc >= 0.0f) && (cc < 96.0f);
      float fl = fminf(fmaxf(floorf(cc),0.0f),94.0f);
      float fr = __fsub_rn(cc, fl);
      int ri = (int)fl;
      rws[2*s]=ri; rws[2*s+1]=ri+1;
      wts[2*s]  = vv ? __fsub_rn(1.0f,fr) : 0.0f;
      wts[2*s+1]= vv ? fr : 0.0f;
      nv += vv?1:0;
    }
    float sc = ok ? (1.0f/(float)nv) : 0.0f;
    int cr[6]; float cw[6]; int n=0;
    for (int k=0;k<6;++k){
      float wk=wts[k]; if (wk==0.0f) continue;
      if (n>0 && cr[n-1]==rws[k]) cw[n-1]+=wk;
      else { cr[n]=rws[k]; cw[n]=wk; ++n; }
    }
    const int mul = isrow ? Ww : 1;
    for (int k=0;k<n;++k){
      int off = cr[k]*mul;
      float wv = cw[k]*sc;
      if (isrow){ s_roff[p][k]=off; s_rw[p][k]=wv; }
      else      { s_coff[p][k]=off; s_cw[p][k]=wv; }
    }
  }
  __syncthreads();

  const float* f0 = feat + ((size_t)s_b*Cc + t)*HWc;
  float awin[5];
  for (int ph=0; ph<AH; ++ph){
    float binrow[AH];
    #pragma unroll
    for (int pw=0; pw<AH; ++pw){
      float acc = 0.0f;
      #pragma unroll
      for (int ai=0; ai<6; ++ai){
        float ra = s_rw[ph][ai];
        if (ra == 0.0f) continue;
        int ro = s_roff[ph][ai];
        #pragma unroll
        for (int bi=0; bi<6; ++bi){
          float cb = s_cw[pw][bi];
          if (cb == 0.0f) continue;
          acc = fmaf(ra*cb, f0[ro + s_coff[pw][bi]], acc);
        }
      }
      binrow[pw] = acc;
    }
    float rm[5];
    #pragma unroll
    for (int ox=0; ox<5; ++ox)
      rm[ox] = fmaxf(fmaxf(binrow[2*ox], binrow[2*ox+1]), binrow[2*ox+2]);
    if (ph == 0){
      #pragma unroll
      for (int ox=0; ox<5; ++ox) awin[ox] = rm[ox];
    } else if (ph & 1){
      #pragma unroll
      for (int ox=0; ox<5; ++ox) awin[ox] = fmaxf(awin[ox], rm[ox]);
    } else {
      int oy = (ph-2) >> 1;
      #pragma unroll
      for (int ox=0; ox<5; ++ox){
        s_out[t*25 + oy*5 + ox] = fmaxf(awin[ox], rm[ox]);
        awin[ox] = rm[ox];
      }
    }
  }
  __syncthreads();

  float4* dst = (float4*)(out + (size_t)r*(Cc*25));
  const float4* src = (const float4*)s_out;
  for (int k=t; k<(Cc*25)/4; k+=512) dst[k]=src[k];
}

extern "C" void kernel_launch(void* const* d_in, const int* in_sizes, int n_in,
                              void* d_out, int out_size, void* d_ws, size_t ws_size,
                              hipStream_t stream)
{
  (void)in_sizes; (void)n_in; (void)out_size;
  const float* feat = (const float*)d_in[0];
  const float* rois = (const float*)d_in[1];
  float* out = (float*)d_out;
  const size_t need = (size_t)Bn*HWc*Cc*sizeof(u16);   // 37.75 MB bf16 NHWC
  if (ws_size >= need){
    u32* ws = (u32*)d_ws;
    dim3 g(HWc/128, Cc/128, Bn);
    transpose_kernel<<<g, 256, 0, stream>>>(feat, ws);
    roi_align_max_nhwc<<<Rr*2, 128, 0, stream>>>(ws, rois, out);
  } else {
    roi_align_max_nchw<<<Rr, 512, 0, stream>>>(feat, rois, out);
  }
}